// Round 16
// baseline (1586.577 us; speedup 1.0000x reference)
//
#include <hip/hip_runtime.h>
#include <hip/hip_bf16.h>

#define N_NODES 50000
#define E_EDGES 600000
#define IN_CH 128
#define HID 256
#define OUT_CH 64
#define NREL 8

typedef __attribute__((ext_vector_type(8))) short bf16x8;
typedef __attribute__((ext_vector_type(4))) float f32x4;

__device__ __forceinline__ float bf2f(unsigned short u) {
    union { unsigned int i; float f; } x; x.i = ((unsigned int)u) << 16; return x.f;
}
__device__ __forceinline__ unsigned short f2bf(float f) {
    __hip_bfloat16 b = __float2bfloat16(f);
    return *reinterpret_cast<unsigned short*>(&b);
}
__device__ __forceinline__ void gload_lds16(const void* g, void* l) {
    __builtin_amdgcn_global_load_lds(
        (const __attribute__((address_space(1))) unsigned int*)g,
        (__attribute__((address_space(3))) unsigned int*)l, 16, 0, 0);
}

// ---------------------------------------------------------------------------
// CSR construction (deterministic): histogram -> 3-phase parallel scan ->
// placement -> per-node WAVE-PARALLEL rank sort by key (rel<<16|src) with
// fused ballot-based relation-segment bounds relOffs[N][9].
// ---------------------------------------------------------------------------
__global__ void k_deg(const int* __restrict__ dst, int* __restrict__ deg) {
    int e = blockIdx.x * blockDim.x + threadIdx.x;
    if (e < E_EDGES) atomicAdd(&deg[dst[e]], 1);
}

__global__ __launch_bounds__(256) void k_scanA(const int* __restrict__ deg,
                                               int* __restrict__ offs,
                                               int* __restrict__ bsum) {
    __shared__ int wexcl[4];
    const int tid = threadIdx.x;
    const int lane = tid & 63;
    const int wid = tid >> 6;
    const int i = blockIdx.x * 256 + tid;
    const int v = (i < N_NODES) ? deg[i] : 0;
    int incl = v;
#pragma unroll
    for (int s = 1; s < 64; s <<= 1) {
        int t = __shfl_up(incl, s);
        if (lane >= s) incl += t;
    }
    __shared__ int wsum[4];
    if (lane == 63) wsum[wid] = incl;
    __syncthreads();
    if (tid == 0) {
        int run = 0;
#pragma unroll
        for (int w = 0; w < 4; w++) { wexcl[w] = run; run += wsum[w]; }
        bsum[blockIdx.x] = run;
    }
    __syncthreads();
    if (i < N_NODES) offs[i] = wexcl[wid] + incl - v;
}

__global__ __launch_bounds__(256) void k_scanB(int* __restrict__ bsum, int nb) {
    __shared__ int wexcl[4];
    __shared__ int wsum[4];
    const int tid = threadIdx.x;
    const int lane = tid & 63;
    const int wid = tid >> 6;
    const int v = (tid < nb) ? bsum[tid] : 0;
    int incl = v;
#pragma unroll
    for (int s = 1; s < 64; s <<= 1) {
        int t = __shfl_up(incl, s);
        if (lane >= s) incl += t;
    }
    if (lane == 63) wsum[wid] = incl;
    __syncthreads();
    if (tid == 0) {
        int run = 0;
#pragma unroll
        for (int w = 0; w < 4; w++) { wexcl[w] = run; run += wsum[w]; }
    }
    __syncthreads();
    if (tid < nb) bsum[tid] = wexcl[wid] + incl - v;
}

__global__ __launch_bounds__(256) void k_scanC(int* __restrict__ offs,
                                               const int* __restrict__ bsum) {
    const int i = blockIdx.x * 256 + threadIdx.x;
    if (i < N_NODES) offs[i] += bsum[blockIdx.x];
    if (i == 0) offs[N_NODES] = E_EDGES;
}

__global__ void k_place(const int* __restrict__ src, const int* __restrict__ dst,
                        const int* __restrict__ etype, const int* __restrict__ offs,
                        int* __restrict__ cursor, int* __restrict__ ekey) {
    int e = blockIdx.x * blockDim.x + threadIdx.x;
    if (e < E_EDGES) {
        int d = dst[e];
        int p = atomicAdd(&cursor[d], 1);
        ekey[offs[d] + p] = (etype[e] << 16) | src[e];
    }
}

// Wave-per-node rank sort (stable, bijective; deg <= 64 fast path) with
// fused segment-bounds: counts per relation via ballot (order-independent).
__global__ __launch_bounds__(256) void k_wsort(const int* __restrict__ offs,
                                               int* __restrict__ ekey,
                                               int* __restrict__ relOffs) {
    const int w = threadIdx.x >> 6;
    const int t = threadIdx.x & 63;
    const int i = blockIdx.x * 4 + w;
    if (i >= N_NODES) return;
    const int lo = offs[i], hi = offs[i + 1];
    const int deg = hi - lo;
    if (deg == 0) {
        if (t < 9) relOffs[i * 9 + t] = lo;
        return;
    }
    if (deg <= 64) {
        const int key = (t < deg) ? ekey[lo + t] : 0x7FFFFFFF;
        int rank = 0;
#pragma unroll
        for (int s = 0; s < 64; s++) {
            const int ok = __shfl(key, s);
            rank += (int)((ok < key) | ((ok == key) & (s < t)));
        }
        if (t < deg) ekey[lo + rank] = key;
        const int rel = key >> 16;  // pad lanes: 0x7FFF, never matches r
        if (t == 0) relOffs[i * 9] = lo;
        int run = lo;
#pragma unroll
        for (int r = 0; r < NREL; r++) {
            unsigned long long b = __ballot((t < deg) && (rel == r));
            run += (int)__popcll(b);
            if (t == 0) relOffs[i * 9 + r + 1] = run;
        }
    } else if (t == 0) {
        // correctness-only fallback (never taken for Poisson(12) degrees)
        for (int a = lo + 1; a < hi; a++) {
            int k = ekey[a];
            int b = a - 1;
            while (b >= lo && ekey[b] > k) { ekey[b + 1] = ekey[b]; b--; }
            ekey[b + 1] = k;
        }
        int p = lo;
        relOffs[i * 9] = lo;
#pragma unroll
        for (int r = 0; r < NREL; r++) {
            while (p < hi && (ekey[p] >> 16) == r) p++;
            relOffs[i * 9 + r + 1] = p;
        }
    }
}

// ---------------------------------------------------------------------------
// Fused prep: x->bf16 | Wt1 | Wt2 | linWt split-W (hi rows 0..63, lo rows
// 64..127: lo = bf16(w - float(hi)) -> reconstructs fp32 W to ~2^-17).
// ---------------------------------------------------------------------------
#define PREP_CVT 6250
#define PREP_WT1 1152
#define PREP_WT2 2304
#define PREP_WT3 128
__global__ __launch_bounds__(256) void k_prep(const float* __restrict__ x,
                                              unsigned short* __restrict__ xb,
                                              const float* __restrict__ root1,
                                              const float* __restrict__ W1,
                                              unsigned short* __restrict__ Wt1,
                                              const float* __restrict__ root2,
                                              const float* __restrict__ W2,
                                              unsigned short* __restrict__ Wt2,
                                              const float* __restrict__ linW,
                                              unsigned short* __restrict__ linWt) {
    const int b = blockIdx.x;
    if (b < PREP_CVT) {
        int i = b * 256 + threadIdx.x;
        float4 v = *(const float4*)&x[i * 4];
        short4 o;
        o.x = (short)f2bf(v.x); o.y = (short)f2bf(v.y);
        o.z = (short)f2bf(v.z); o.w = (short)f2bf(v.w);
        *(short4*)&xb[i * 4] = o;
    } else if (b < PREP_CVT + PREP_WT1) {
        int idx = (b - PREP_CVT) * 256 + threadIdx.x;
        int c = idx / 1152, k = idx % 1152;
        float v = (k < IN_CH) ? root1[k * 256 + c] : W1[(size_t)(k - IN_CH) * 256 + c];
        Wt1[idx] = f2bf(v);
    } else if (b < PREP_CVT + PREP_WT1 + PREP_WT2) {
        int idx = (b - PREP_CVT - PREP_WT1) * 256 + threadIdx.x;
        int c = idx / 2304, k = idx % 2304;
        float v = (k < HID) ? root2[k * 256 + c] : W2[(size_t)(k - HID) * 256 + c];
        Wt2[idx] = f2bf(v);
    } else {
        int idx = (b - PREP_CVT - PREP_WT1 - PREP_WT2) * 256 + threadIdx.x;
        int rp = idx / 256, k = idx % 256;  // rp in [0,128)
        int c = rp & 63;
        float w = linW[k * OUT_CH + c];
        unsigned short hi = f2bf(w);
        linWt[idx] = (rp < 64) ? hi : f2bf(w - bf2f(hi));
    }
}

// ---------------------------------------------------------------------------
// FUSED agg+GEMM: hbOut[M,256] = relu([Aroot | AGG(Aroot)] @ Wt + bias).
// The A-operand's agg region is PRODUCED in-kernel per K-step (no agg
// buffer, no HBM round-trip). Tile 128x128, BK=64, 4 waves.
//  - root steps (k0 < rootK): A staged via global_load_lds (pre-swizzled
//    source, proven path).
//  - agg steps: K-step = 64-channel slice [c0,c0+64) of relation rel.
//    Each wave produces its 32 rows: 8-row register groups, bounds
//    broadcast-read from relOffs (wave-uniform, L1-hot), keys broadcast
//    loads, 2B/lane coalesced gathers, clamped idx + predicated add
//    (identical per-channel fp32 accumulation order as the old k_agg8 ->
//    bit-identical results). ds_write_b16 at the same XOR-swizzle position
//    the staged path used, so MFMA fragment reads are unchanged.
//  - B double-buffered via global_load_lds (unchanged).
// LDS 48KB -> 3 blocks/CU. Bijective XCD block swizzle, holes early-exit.
// ---------------------------------------------------------------------------
template <int CH>
__global__ __launch_bounds__(256) void k_fgemm(
    const unsigned short* __restrict__ Aroot,   // [N, CH] bf16 (also gather src)
    const unsigned short* __restrict__ Wt, int ldWt, int Ktot,
    const int* __restrict__ relOffs, const int* __restrict__ ekey,
    const float* __restrict__ bias, unsigned short* __restrict__ hbOut, int M,
    int rowsPerXcd) {
    __shared__ __align__(16) unsigned short Al[128 * 64];
    __shared__ __align__(16) unsigned short Bl[2][128 * 64];
    const int rootK = CH;
    const int p = blockIdx.x;
    const int xcd = p & 7;
    const int col = (p >> 3) & 1;
    const int rIdx = p >> 4;
    const int row = xcd * rowsPerXcd + rIdx;
    if (row * 128 >= M) return;
    const int bm = row * 128;
    const int bn = col * 128;
    const int tid = threadIdx.x;
    const int wv = tid >> 6, ln = tid & 63;
    const int wr = (wv & 1) * 64;
    const int wc = (wv >> 1) * 64;
    const int lg = ln >> 4;
    const int lr = ln & 15;

    f32x4 acc[4][4];
#pragma unroll
    for (int m = 0; m < 4; m++)
#pragma unroll
        for (int n = 0; n < 4; n++) acc[m][n] = (f32x4){0.f, 0.f, 0.f, 0.f};

    int baseR[4], baseB[4];
#pragma unroll
    for (int q = 0; q < 4; q++) {
        int t = (wv * 4 + q) * 64 + ln;
        int r = t >> 3, ps = t & 7;
        int slog = ps ^ (r & 7);
        int rg = bm + r; if (rg > M - 1) rg = M - 1;
        baseR[q] = rg * CH + slog * 8;
        baseB[q] = (bn + r) * ldWt + slog * 8;
    }

    auto stageB = [&](int k0, int buf) {
#pragma unroll
        for (int q = 0; q < 4; q++)
            gload_lds16(Wt + baseB[q] + k0, &Bl[buf][(wv * 4 + q) * 512]);
    };
    auto stageAroot = [&](int k0) {
#pragma unroll
        for (int q = 0; q < 4; q++)
            gload_lds16(Aroot + baseR[q] + k0, &Al[(wv * 4 + q) * 512]);
    };

    const int nt = Ktot >> 6;
    stageB(0, 0);
    int cur = 0;

    for (int t = 0; t < nt; ++t) {
        const int k0 = t << 6;
        if (t + 1 < nt) stageB((t + 1) << 6, cur ^ 1);

        if (k0 < rootK) {
            stageAroot(k0);
        } else {
            // ---- produce A-tile: mean_{rel}(Aroot)[rows, c0..c0+63] ----
            const int ka = k0 - rootK;
            const int rel = ka / CH;          // CH is constexpr power of 2
            const int c0 = ka & (CH - 1);
            const unsigned short* srcF = Aroot + c0 + ln;
            const int r0 = wv * 32;
#pragma unroll
            for (int g = 0; g < 4; g++) {
                int sA[8], eA[8];
                float ac[8];
#pragma unroll
                for (int rr = 0; rr < 8; rr++) {
                    int node = bm + r0 + g * 8 + rr;
                    if (node > M - 1) node = M - 1;
                    sA[rr] = relOffs[node * 9 + rel];
                    eA[rr] = relOffs[node * 9 + rel + 1];
                    ac[rr] = 0.f;
                }
                int mx = 0;
#pragma unroll
                for (int rr = 0; rr < 8; rr++) {
                    int l = eA[rr] - sA[rr];
                    if (l > mx) mx = l;
                }
                for (int q = 0; q < mx; q++) {
#pragma unroll
                    for (int rr = 0; rr < 8; rr++) {
                        int jj = sA[rr] + q;
                        int lim = eA[rr] - 1;
                        if (lim < 0) lim = 0;
                        if (jj > lim) jj = lim;
                        const int key = ekey[jj] & 0xFFFF;  // wave-uniform bcast
                        const float v = bf2f(srcF[(size_t)key * CH]);
                        ac[rr] += (sA[rr] + q < eA[rr]) ? v : 0.f;
                    }
                }
#pragma unroll
                for (int rr = 0; rr < 8; rr++) {
                    const int len = eA[rr] - sA[rr];
                    const float inv = (len > 0) ? 1.0f / (float)len : 0.0f;
                    const int ii = r0 + g * 8 + rr;
                    Al[ii * 64 + (((ln >> 3) ^ (ii & 7)) << 3) + (ln & 7)] =
                        f2bf(ac[rr] * inv);
                }
            }
        }

        __syncthreads();  // drains vmcnt+lgkm: A ready (staged or produced), B(t) ready
        __builtin_amdgcn_s_setprio(1);
#pragma unroll
        for (int kk = 0; kk < 2; kk++) {
            bf16x8 af[4], bfr[4];
#pragma unroll
            for (int m = 0; m < 4; m++) {
                int r = wr + 16 * m + lr;
                int ph = (kk * 4 + lg) ^ (r & 7);
                af[m] = *(const bf16x8*)&Al[r * 64 + ph * 8];
            }
#pragma unroll
            for (int n = 0; n < 4; n++) {
                int c = wc + 16 * n + lr;
                int ph = (kk * 4 + lg) ^ (c & 7);
                bfr[n] = *(const bf16x8*)&Bl[cur][c * 64 + ph * 8];
            }
#pragma unroll
            for (int m = 0; m < 4; m++)
#pragma unroll
                for (int n = 0; n < 4; n++)
                    acc[m][n] = __builtin_amdgcn_mfma_f32_16x16x32_bf16(
                        af[m], bfr[n], acc[m][n], 0, 0, 0);
        }
        __builtin_amdgcn_s_setprio(0);
        __syncthreads();  // all reads of Al / Bl[cur] done before overwrite
        cur ^= 1;
    }

    // C/D: col = lane&15, row = (lane>>4)*4 + reg  [m89/m91]
#pragma unroll
    for (int m = 0; m < 4; m++) {
#pragma unroll
        for (int reg = 0; reg < 4; reg++) {
            int r = bm + wr + 16 * m + lg * 4 + reg;
            if (r >= M) continue;
#pragma unroll
            for (int n = 0; n < 4; n++) {
                int c = bn + wc + 16 * n + lr;
                float v = acc[m][n][reg] + bias[c];
                hbOut[(size_t)r * 256 + c] = f2bf(fmaxf(v, 0.f));
            }
        }
    }
}

// ---------------------------------------------------------------------------
// Final linear [256->64] via MFMA with split-W + fused log_softmax.
// ---------------------------------------------------------------------------
__global__ __launch_bounds__(256) void k_final3(const unsigned short* __restrict__ h,
                                                const unsigned short* __restrict__ linWt,
                                                const float* __restrict__ bias,
                                                float* __restrict__ out, int M) {
    __shared__ __align__(16) unsigned short Al[128 * 64];
    __shared__ __align__(16) unsigned short Bl[128 * 64];
    const int bm = blockIdx.x * 128;
    const int tid = threadIdx.x;
    const int wv = tid >> 6, ln = tid & 63;
    const int wr = wv * 32;
    const int lg = ln >> 4;
    const int lr = ln & 15;

    f32x4 acc[2][8];
#pragma unroll
    for (int m = 0; m < 2; m++)
#pragma unroll
        for (int n = 0; n < 8; n++) acc[m][n] = (f32x4){0.f, 0.f, 0.f, 0.f};

    int baseA[4], baseB[4];
#pragma unroll
    for (int q = 0; q < 4; q++) {
        int t = (wv * 4 + q) * 64 + ln;
        int r = t >> 3, ps = t & 7;
        int slog = ps ^ (r & 7);
        int rg = bm + r; if (rg > M - 1) rg = M - 1;
        baseA[q] = rg * HID + slog * 8;
        baseB[q] = r * HID + slog * 8;  // 128 stacked hi/lo rows, ld=256
    }

    for (int t = 0; t < 4; ++t) {
        if (t > 0) __syncthreads();
        const int k0 = t << 6;
#pragma unroll
        for (int q = 0; q < 4; q++)
            gload_lds16(h + baseA[q] + k0, &Al[(wv * 4 + q) * 512]);
#pragma unroll
        for (int q = 0; q < 4; q++)
            gload_lds16(linWt + baseB[q] + k0, &Bl[(wv * 4 + q) * 512]);
        asm volatile("s_waitcnt vmcnt(0)" ::: "memory");
        __syncthreads();
#pragma unroll
        for (int kk = 0; kk < 2; kk++) {
            bf16x8 af[2], bfr[8];
#pragma unroll
            for (int m = 0; m < 2; m++) {
                int r = wr + 16 * m + lr;
                int ph = (kk * 4 + lg) ^ (r & 7);
                af[m] = *(const bf16x8*)&Al[r * 64 + ph * 8];
            }
#pragma unroll
            for (int n = 0; n < 8; n++) {
                int c = n * 16 + lr;
                int ph = (kk * 4 + lg) ^ (c & 7);
                bfr[n] = *(const bf16x8*)&Bl[c * 64 + ph * 8];
            }
#pragma unroll
            for (int m = 0; m < 2; m++)
#pragma unroll
                for (int n = 0; n < 8; n++)
                    acc[m][n] = __builtin_amdgcn_mfma_f32_16x16x32_bf16(
                        af[m], bfr[n], acc[m][n], 0, 0, 0);
        }
    }

    float b4[4];
#pragma unroll
    for (int n = 0; n < 4; n++) b4[n] = bias[n * 16 + lr];
#pragma unroll
    for (int m = 0; m < 2; m++) {
#pragma unroll
        for (int reg = 0; reg < 4; reg++) {
            const int row = bm + wr + 16 * m + lg * 4 + reg;
            float v0 = acc[m][0][reg] + acc[m][4][reg] + b4[0];
            float v1 = acc[m][1][reg] + acc[m][5][reg] + b4[1];
            float v2 = acc[m][2][reg] + acc[m][6][reg] + b4[2];
            float v3 = acc[m][3][reg] + acc[m][7][reg] + b4[3];
            float mx = fmaxf(fmaxf(v0, v1), fmaxf(v2, v3));
#pragma unroll
            for (int s = 1; s < 16; s <<= 1) mx = fmaxf(mx, __shfl_xor(mx, s));
            float sum = expf(v0 - mx) + expf(v1 - mx) + expf(v2 - mx) + expf(v3 - mx);
#pragma unroll
            for (int s = 1; s < 16; s <<= 1) sum += __shfl_xor(sum, s);
            const float lse = mx + logf(sum);
            if (row < M) {
                float* orow = out + (size_t)row * OUT_CH + lr;
                orow[0]  = v0 - lse;
                orow[16] = v1 - lse;
                orow[32] = v2 - lse;
                orow[48] = v3 - lse;
            }
        }
    }
}

// ---------------------------------------------------------------------------
extern "C" void kernel_launch(void* const* d_in, const int* in_sizes, int n_in,
                              void* d_out, int out_size, void* d_ws, size_t ws_size,
                              hipStream_t stream) {
    const float* x     = (const float*)d_in[0];
    const int*   eidx  = (const int*)d_in[1];
    const int*   etype = (const int*)d_in[2];
    const float* W1    = (const float*)d_in[3];
    const float* root1 = (const float*)d_in[4];
    const float* b1    = (const float*)d_in[5];
    const float* W2    = (const float*)d_in[6];
    const float* root2 = (const float*)d_in[7];
    const float* b2    = (const float*)d_in[8];
    const float* linW  = (const float*)d_in[9];
    const float* linb  = (const float*)d_in[10];
    float* out = (float*)d_out;
    const int* srcI = eidx;
    const int* dstI = eidx + E_EDGES;

    char* ws = (char*)d_ws;
    size_t off = 0;
    auto alloc = [&](size_t bytes) {
        size_t o = off;
        off += (bytes + 255) & ~(size_t)255;
        return ws + o;
    };
    unsigned short* xb    = (unsigned short*)alloc((size_t)N_NODES * IN_CH * 2);
    unsigned short* hb1   = (unsigned short*)alloc((size_t)N_NODES * HID * 2);
    unsigned short* hb2   = (unsigned short*)alloc((size_t)N_NODES * HID * 2);
    unsigned short* Wt1   = (unsigned short*)alloc((size_t)256 * 1152 * 2);
    unsigned short* Wt2   = (unsigned short*)alloc((size_t)256 * 2304 * 2);
    unsigned short* linWt = (unsigned short*)alloc((size_t)128 * 256 * 2);
    int* deg     = (int*)alloc((size_t)N_NODES * 4);
    int* cursor  = (int*)alloc((size_t)N_NODES * 4);
    int* offs    = (int*)alloc((size_t)(N_NODES + 1) * 4);
    int* ekey    = (int*)alloc((size_t)E_EDGES * 4);
    int* relOffs = (int*)alloc((size_t)N_NODES * 9 * 4);
    int* bsum    = (int*)alloc((size_t)256 * 4);

    k_prep<<<PREP_CVT + PREP_WT1 + PREP_WT2 + PREP_WT3, 256, 0, stream>>>(
        x, xb, root1, W1, Wt1, root2, W2, Wt2, linW, linWt);
    hipMemsetAsync(deg, 0, (size_t)N_NODES * 4, stream);
    hipMemsetAsync(cursor, 0, (size_t)N_NODES * 4, stream);
    k_deg<<<(E_EDGES + 255) / 256, 256, 0, stream>>>(dstI, deg);
    const int nb = (N_NODES + 255) / 256;  // 196
    k_scanA<<<nb, 256, 0, stream>>>(deg, offs, bsum);
    k_scanB<<<1, 256, 0, stream>>>(bsum, nb);
    k_scanC<<<nb, 256, 0, stream>>>(offs, bsum);
    k_place<<<(E_EDGES + 255) / 256, 256, 0, stream>>>(srcI, dstI, etype, offs, cursor, ekey);
    k_wsort<<<(N_NODES + 3) / 4, 256, 0, stream>>>(offs, ekey, relOffs);

    auto mkGrid = [](int M, int& rpx) {
        int nRow = (M + 127) / 128;
        rpx = (nRow + 7) / 8;
        return 16 * rpx;
    };

    int rpx;
    const int nG = mkGrid(N_NODES, rpx);

    // ---- Layer 1: ONE fused agg+GEMM, K = 128 + 1024 ----
    k_fgemm<IN_CH><<<nG, 256, 0, stream>>>(xb, Wt1, 1152, 1152, relOffs, ekey,
                                           b1, hb1, N_NODES, rpx);

    // ---- Layer 2: ONE fused agg+GEMM, K = 256 + 2048 (no chunking) ----
    k_fgemm<HID><<<nG, 256, 0, stream>>>(hb1, Wt2, 2304, 2304, relOffs, ekey,
                                         b2, hb2, N_NODES, rpx);

    // ---- Final linear (MFMA, split-W) + log_softmax ----
    k_final3<<<(N_NODES + 127) / 128, 256, 0, stream>>>(hb2, linWt, linb, out, N_NODES);
}

// Round 17
// 396.704 us; speedup vs baseline: 3.9994x; 3.9994x over previous
//
#include <hip/hip_runtime.h>
#include <hip/hip_bf16.h>

#define N_NODES 50000
#define E_EDGES 600000
#define IN_CH 128
#define HID 256
#define OUT_CH 64
#define NREL 8
#define HALF1 25000

typedef __attribute__((ext_vector_type(8))) short bf16x8;
typedef __attribute__((ext_vector_type(4))) float f32x4;

__device__ __forceinline__ float bf2f(unsigned short u) {
    union { unsigned int i; float f; } x; x.i = ((unsigned int)u) << 16; return x.f;
}
__device__ __forceinline__ unsigned short f2bf(float f) {
    __hip_bfloat16 b = __float2bfloat16(f);
    return *reinterpret_cast<unsigned short*>(&b);
}
__device__ __forceinline__ void gload_lds16(const void* g, void* l) {
    __builtin_amdgcn_global_load_lds(
        (const __attribute__((address_space(1))) unsigned int*)g,
        (__attribute__((address_space(3))) unsigned int*)l, 16, 0, 0);
}

// ---------------------------------------------------------------------------
// CSR construction (deterministic): histogram -> 3-phase parallel scan ->
// placement -> per-node WAVE-PARALLEL rank sort by key (rel<<16|src) with
// fused ballot-based relation-segment bounds relOffs[N][9].
// ---------------------------------------------------------------------------
__global__ void k_deg(const int* __restrict__ dst, int* __restrict__ deg) {
    int e = blockIdx.x * blockDim.x + threadIdx.x;
    if (e < E_EDGES) atomicAdd(&deg[dst[e]], 1);
}

__global__ __launch_bounds__(256) void k_scanA(const int* __restrict__ deg,
                                               int* __restrict__ offs,
                                               int* __restrict__ bsum) {
    __shared__ int wexcl[4];
    const int tid = threadIdx.x;
    const int lane = tid & 63;
    const int wid = tid >> 6;
    const int i = blockIdx.x * 256 + tid;
    const int v = (i < N_NODES) ? deg[i] : 0;
    int incl = v;
#pragma unroll
    for (int s = 1; s < 64; s <<= 1) {
        int t = __shfl_up(incl, s);
        if (lane >= s) incl += t;
    }
    __shared__ int wsum[4];
    if (lane == 63) wsum[wid] = incl;
    __syncthreads();
    if (tid == 0) {
        int run = 0;
#pragma unroll
        for (int w = 0; w < 4; w++) { wexcl[w] = run; run += wsum[w]; }
        bsum[blockIdx.x] = run;
    }
    __syncthreads();
    if (i < N_NODES) offs[i] = wexcl[wid] + incl - v;
}

__global__ __launch_bounds__(256) void k_scanB(int* __restrict__ bsum, int nb) {
    __shared__ int wexcl[4];
    __shared__ int wsum[4];
    const int tid = threadIdx.x;
    const int lane = tid & 63;
    const int wid = tid >> 6;
    const int v = (tid < nb) ? bsum[tid] : 0;
    int incl = v;
#pragma unroll
    for (int s = 1; s < 64; s <<= 1) {
        int t = __shfl_up(incl, s);
        if (lane >= s) incl += t;
    }
    if (lane == 63) wsum[wid] = incl;
    __syncthreads();
    if (tid == 0) {
        int run = 0;
#pragma unroll
        for (int w = 0; w < 4; w++) { wexcl[w] = run; run += wsum[w]; }
    }
    __syncthreads();
    if (tid < nb) bsum[tid] = wexcl[wid] + incl - v;
}

__global__ __launch_bounds__(256) void k_scanC(int* __restrict__ offs,
                                               const int* __restrict__ bsum) {
    const int i = blockIdx.x * 256 + threadIdx.x;
    if (i < N_NODES) offs[i] += bsum[blockIdx.x];
    if (i == 0) offs[N_NODES] = E_EDGES;
}

__global__ void k_place(const int* __restrict__ src, const int* __restrict__ dst,
                        const int* __restrict__ etype, const int* __restrict__ offs,
                        int* __restrict__ cursor, int* __restrict__ ekey) {
    int e = blockIdx.x * blockDim.x + threadIdx.x;
    if (e < E_EDGES) {
        int d = dst[e];
        int p = atomicAdd(&cursor[d], 1);
        ekey[offs[d] + p] = (etype[e] << 16) | src[e];
    }
}

// Wave-per-node rank sort (stable, bijective; deg <= 64 fast path) with
// fused segment-bounds: counts per relation via ballot (order-independent).
__global__ __launch_bounds__(256) void k_wsort(const int* __restrict__ offs,
                                               int* __restrict__ ekey,
                                               int* __restrict__ relOffs) {
    const int w = threadIdx.x >> 6;
    const int t = threadIdx.x & 63;
    const int i = blockIdx.x * 4 + w;
    if (i >= N_NODES) return;
    const int lo = offs[i], hi = offs[i + 1];
    const int deg = hi - lo;
    if (deg == 0) {
        if (t < 9) relOffs[i * 9 + t] = lo;
        return;
    }
    if (deg <= 64) {
        const int key = (t < deg) ? ekey[lo + t] : 0x7FFFFFFF;
        int rank = 0;
#pragma unroll
        for (int s = 0; s < 64; s++) {
            const int ok = __shfl(key, s);
            rank += (int)((ok < key) | ((ok == key) & (s < t)));
        }
        if (t < deg) ekey[lo + rank] = key;
        const int rel = key >> 16;  // pad lanes: 0x7FFF, never matches r
        if (t == 0) relOffs[i * 9] = lo;
        int run = lo;
#pragma unroll
        for (int r = 0; r < NREL; r++) {
            unsigned long long b = __ballot((t < deg) && (rel == r));
            run += (int)__popcll(b);
            if (t == 0) relOffs[i * 9 + r + 1] = run;
        }
    } else if (t == 0) {
        // correctness-only fallback (never taken for Poisson(12) degrees)
        for (int a = lo + 1; a < hi; a++) {
            int k = ekey[a];
            int b = a - 1;
            while (b >= lo && ekey[b] > k) { ekey[b + 1] = ekey[b]; b--; }
            ekey[b + 1] = k;
        }
        int p = lo;
        relOffs[i * 9] = lo;
#pragma unroll
        for (int r = 0; r < NREL; r++) {
            while (p < hi && (ekey[p] >> 16) == r) p++;
            relOffs[i * 9 + r + 1] = p;
        }
    }
}

// ---------------------------------------------------------------------------
// Fused prep: x->bf16 | Wt1 | Wt2 | linWt split-W (hi rows 0..63, lo rows
// 64..127: lo = bf16(w - float(hi)) -> reconstructs fp32 W to ~2^-17).
// ---------------------------------------------------------------------------
#define PREP_CVT 6250
#define PREP_WT1 1152
#define PREP_WT2 2304
#define PREP_WT3 128
__global__ __launch_bounds__(256) void k_prep(const float* __restrict__ x,
                                              unsigned short* __restrict__ xb,
                                              const float* __restrict__ root1,
                                              const float* __restrict__ W1,
                                              unsigned short* __restrict__ Wt1,
                                              const float* __restrict__ root2,
                                              const float* __restrict__ W2,
                                              unsigned short* __restrict__ Wt2,
                                              const float* __restrict__ linW,
                                              unsigned short* __restrict__ linWt) {
    const int b = blockIdx.x;
    if (b < PREP_CVT) {
        int i = b * 256 + threadIdx.x;
        float4 v = *(const float4*)&x[i * 4];
        short4 o;
        o.x = (short)f2bf(v.x); o.y = (short)f2bf(v.y);
        o.z = (short)f2bf(v.z); o.w = (short)f2bf(v.w);
        *(short4*)&xb[i * 4] = o;
    } else if (b < PREP_CVT + PREP_WT1) {
        int idx = (b - PREP_CVT) * 256 + threadIdx.x;
        int c = idx / 1152, k = idx % 1152;
        float v = (k < IN_CH) ? root1[k * 256 + c] : W1[(size_t)(k - IN_CH) * 256 + c];
        Wt1[idx] = f2bf(v);
    } else if (b < PREP_CVT + PREP_WT1 + PREP_WT2) {
        int idx = (b - PREP_CVT - PREP_WT1) * 256 + threadIdx.x;
        int c = idx / 2304, k = idx % 2304;
        float v = (k < HID) ? root2[k * 256 + c] : W2[(size_t)(k - HID) * 256 + c];
        Wt2[idx] = f2bf(v);
    } else {
        int idx = (b - PREP_CVT - PREP_WT1 - PREP_WT2) * 256 + threadIdx.x;
        int rp = idx / 256, k = idx % 256;  // rp in [0,128)
        int c = rp & 63;
        float w = linW[k * OUT_CH + c];
        unsigned short hi = f2bf(w);
        linWt[idx] = (rp < 64) ? hi : f2bf(w - bf2f(hi));
    }
}

// ---------------------------------------------------------------------------
// Mean aggregation (PROVEN rounds 11-15): one wave per node, lane owns CH/64
// channels. All keys preloaded once (deg <= 64 fast path), per-relation
// unroll-2 gather with explicit odd tail. Serial fallback deg > 64.
// ---------------------------------------------------------------------------
template <int CH>
__global__ __launch_bounds__(256) void k_agg8(const unsigned short* __restrict__ xin,
                                              const int* __restrict__ relOffs,
                                              const int* __restrict__ ekey,
                                              unsigned short* __restrict__ agg,
                                              int base, int count) {
    const int w = threadIdx.x >> 6;
    const int t = threadIdx.x & 63;
    const int rel_node = blockIdx.x * 4 + w;
    if (rel_node >= count) return;
    const int node = base + rel_node;
    constexpr int VPT = CH / 64;
    const unsigned short* xcol = xin + t * VPT;
    unsigned short* orow = agg + (size_t)rel_node * (NREL * CH) + t * VPT;
    const int* ro = relOffs + node * 9;
    const int lo = ro[0];
    const int deg = ro[8] - lo;

    if (deg == 0) {
#pragma unroll
        for (int r = 0; r < NREL; r++) {
            if (VPT == 4) *(short4*)(orow + r * CH) = make_short4(0, 0, 0, 0);
            else *(short2*)(orow + r * CH) = make_short2(0, 0);
        }
        return;
    }

    if (deg <= 64) {
        const int kv = ekey[lo + ((t < deg) ? t : 0)];
#pragma unroll
        for (int r = 0; r < NREL; r++) {
            const int s = ro[r] - lo, e = ro[r + 1] - lo;
            const int len = e - s;
            float a0 = 0.f, a1 = 0.f, a2 = 0.f, a3 = 0.f;
            int j = s;
            for (; j + 2 <= e; j += 2) {
                const int k0 = __shfl(kv, j) & 0xFFFF;
                const int k1 = __shfl(kv, j + 1) & 0xFFFF;
                if (VPT == 4) {
                    short4 v0 = *(const short4*)(xcol + (size_t)k0 * CH);
                    short4 v1 = *(const short4*)(xcol + (size_t)k1 * CH);
                    a0 += bf2f((unsigned short)v0.x);
                    a1 += bf2f((unsigned short)v0.y);
                    a2 += bf2f((unsigned short)v0.z);
                    a3 += bf2f((unsigned short)v0.w);
                    a0 += bf2f((unsigned short)v1.x);
                    a1 += bf2f((unsigned short)v1.y);
                    a2 += bf2f((unsigned short)v1.z);
                    a3 += bf2f((unsigned short)v1.w);
                } else {
                    short2 v0 = *(const short2*)(xcol + (size_t)k0 * CH);
                    short2 v1 = *(const short2*)(xcol + (size_t)k1 * CH);
                    a0 += bf2f((unsigned short)v0.x);
                    a1 += bf2f((unsigned short)v0.y);
                    a0 += bf2f((unsigned short)v1.x);
                    a1 += bf2f((unsigned short)v1.y);
                }
            }
            if (j < e) {
                const int k0 = __shfl(kv, j) & 0xFFFF;
                if (VPT == 4) {
                    short4 v0 = *(const short4*)(xcol + (size_t)k0 * CH);
                    a0 += bf2f((unsigned short)v0.x);
                    a1 += bf2f((unsigned short)v0.y);
                    a2 += bf2f((unsigned short)v0.z);
                    a3 += bf2f((unsigned short)v0.w);
                } else {
                    short2 v0 = *(const short2*)(xcol + (size_t)k0 * CH);
                    a0 += bf2f((unsigned short)v0.x);
                    a1 += bf2f((unsigned short)v0.y);
                }
            }
            const float inv = (len > 0) ? 1.0f / (float)len : 0.0f;
            if (VPT == 4) {
                short4 o;
                o.x = (short)f2bf(a0 * inv);
                o.y = (short)f2bf(a1 * inv);
                o.z = (short)f2bf(a2 * inv);
                o.w = (short)f2bf(a3 * inv);
                *(short4*)(orow + r * CH) = o;
            } else {
                short2 o;
                o.x = (short)f2bf(a0 * inv);
                o.y = (short)f2bf(a1 * inv);
                *(short2*)(orow + r * CH) = o;
            }
        }
    } else {
#pragma unroll
        for (int r = 0; r < NREL; r++) {
            const int s = ro[r], e = ro[r + 1];
            float a0 = 0.f, a1 = 0.f, a2 = 0.f, a3 = 0.f;
            for (int ee = s; ee < e; ee++) {
                const int k = ekey[ee] & 0xFFFF;
                if (VPT == 4) {
                    short4 v = *(const short4*)(xcol + (size_t)k * CH);
                    a0 += bf2f((unsigned short)v.x);
                    a1 += bf2f((unsigned short)v.y);
                    a2 += bf2f((unsigned short)v.z);
                    a3 += bf2f((unsigned short)v.w);
                } else {
                    short2 v = *(const short2*)(xcol + (size_t)k * CH);
                    a0 += bf2f((unsigned short)v.x);
                    a1 += bf2f((unsigned short)v.y);
                }
            }
            const float inv = (e > s) ? 1.0f / (float)(e - s) : 0.0f;
            if (VPT == 4) {
                short4 o;
                o.x = (short)f2bf(a0 * inv);
                o.y = (short)f2bf(a1 * inv);
                o.z = (short)f2bf(a2 * inv);
                o.w = (short)f2bf(a3 * inv);
                *(short4*)(orow + r * CH) = o;
            } else {
                short2 o;
                o.x = (short)f2bf(a0 * inv);
                o.y = (short)f2bf(a1 * inv);
                *(short2*)(orow + r * CH) = o;
            }
        }
    }
}

// ---------------------------------------------------------------------------
// bf16 MFMA GEMM, 2-phase double-buffered pipeline (round-12/15 proven):
// 128x128 tile, BK=64, 4 waves, XOR-swizzled LDS, bijective XCD swizzle.
// ---------------------------------------------------------------------------
__global__ __launch_bounds__(256) void k_mgemm(
    const unsigned short* __restrict__ Aroot, int rootK, int ldroot,
    const unsigned short* __restrict__ Aagg, int ldagg,
    const unsigned short* __restrict__ Wt, int ldWt, int Ktot,
    const float* __restrict__ bias, unsigned short* __restrict__ hbOut, int M,
    int rowsPerXcd) {
    __shared__ __align__(16) unsigned short Al[2][128 * 64];
    __shared__ __align__(16) unsigned short Bl[2][128 * 64];
    const int p = blockIdx.x;
    const int xcd = p & 7;
    const int col = (p >> 3) & 1;
    const int rIdx = p >> 4;
    const int row = xcd * rowsPerXcd + rIdx;
    if (row * 128 >= M) return;
    const int bm = row * 128;
    const int bn = col * 128;
    const int tid = threadIdx.x;
    const int wv = tid >> 6, ln = tid & 63;
    const int wr = (wv & 1) * 64;
    const int wc = (wv >> 1) * 64;
    const int lg = ln >> 4;
    const int lr = ln & 15;

    f32x4 acc[4][4];
#pragma unroll
    for (int m = 0; m < 4; m++)
#pragma unroll
        for (int n = 0; n < 4; n++) acc[m][n] = (f32x4){0.f, 0.f, 0.f, 0.f};

    int baseR[4], baseG[4], baseB[4];
#pragma unroll
    for (int q = 0; q < 4; q++) {
        int t = (wv * 4 + q) * 64 + ln;
        int r = t >> 3, ps = t & 7;
        int slog = ps ^ (r & 7);
        int rg = bm + r; if (rg > M - 1) rg = M - 1;
        baseR[q] = (rootK > 0) ? (rg * ldroot + slog * 8) : 0;
        baseG[q] = rg * ldagg + slog * 8 - rootK;
        baseB[q] = (bn + r) * ldWt + slog * 8;
    }

    auto stage = [&](int k0, int buf) {
        const bool inRoot = (k0 < rootK);
#pragma unroll
        for (int q = 0; q < 4; q++) {
            const unsigned short* sa =
                inRoot ? (Aroot + baseR[q] + k0) : (Aagg + baseG[q] + k0);
            gload_lds16(sa, &Al[buf][(wv * 4 + q) * 512]);
        }
#pragma unroll
        for (int q = 0; q < 4; q++) {
            gload_lds16(Wt + baseB[q] + k0, &Bl[buf][(wv * 4 + q) * 512]);
        }
    };

    const int nt = Ktot >> 6;
    stage(0, 0);
    asm volatile("s_waitcnt vmcnt(0)" ::: "memory");
    __syncthreads();

    int cur = 0;
    for (int t = 0; t < nt; ++t) {
        if (t + 1 < nt) stage((t + 1) << 6, cur ^ 1);
        __builtin_amdgcn_s_setprio(1);
#pragma unroll
        for (int kk = 0; kk < 2; kk++) {
            bf16x8 af[4], bfr[4];
#pragma unroll
            for (int m = 0; m < 4; m++) {
                int r = wr + 16 * m + lr;
                int ph = (kk * 4 + lg) ^ (r & 7);
                af[m] = *(const bf16x8*)&Al[cur][r * 64 + ph * 8];
            }
#pragma unroll
            for (int n = 0; n < 4; n++) {
                int c = wc + 16 * n + lr;
                int ph = (kk * 4 + lg) ^ (c & 7);
                bfr[n] = *(const bf16x8*)&Bl[cur][c * 64 + ph * 8];
            }
#pragma unroll
            for (int m = 0; m < 4; m++)
#pragma unroll
                for (int n = 0; n < 4; n++)
                    acc[m][n] = __builtin_amdgcn_mfma_f32_16x16x32_bf16(
                        af[m], bfr[n], acc[m][n], 0, 0, 0);
        }
        __builtin_amdgcn_s_setprio(0);
        if (t + 1 < nt) {
            asm volatile("s_waitcnt vmcnt(0)" ::: "memory");
            __syncthreads();
            cur ^= 1;
        }
    }

    // C/D: col = lane&15, row = (lane>>4)*4 + reg  [m89/m91]
#pragma unroll
    for (int m = 0; m < 4; m++) {
#pragma unroll
        for (int reg = 0; reg < 4; reg++) {
            int r = bm + wr + 16 * m + lg * 4 + reg;
            if (r >= M) continue;
#pragma unroll
            for (int n = 0; n < 4; n++) {
                int c = bn + wc + 16 * n + lr;
                float v = acc[m][n][reg] + bias[c];
                hbOut[(size_t)r * 256 + c] = f2bf(fmaxf(v, 0.f));
            }
        }
    }
}

// ---------------------------------------------------------------------------
// Final linear [256->64] via MFMA with split-W + fused log_softmax.
// ---------------------------------------------------------------------------
__global__ __launch_bounds__(256) void k_final3(const unsigned short* __restrict__ h,
                                                const unsigned short* __restrict__ linWt,
                                                const float* __restrict__ bias,
                                                float* __restrict__ out, int M) {
    __shared__ __align__(16) unsigned short Al[128 * 64];
    __shared__ __align__(16) unsigned short Bl[128 * 64];
    const int bm = blockIdx.x * 128;
    const int tid = threadIdx.x;
    const int wv = tid >> 6, ln = tid & 63;
    const int wr = wv * 32;
    const int lg = ln >> 4;
    const int lr = ln & 15;

    f32x4 acc[2][8];
#pragma unroll
    for (int m = 0; m < 2; m++)
#pragma unroll
        for (int n = 0; n < 8; n++) acc[m][n] = (f32x4){0.f, 0.f, 0.f, 0.f};

    int baseA[4], baseB[4];
#pragma unroll
    for (int q = 0; q < 4; q++) {
        int t = (wv * 4 + q) * 64 + ln;
        int r = t >> 3, ps = t & 7;
        int slog = ps ^ (r & 7);
        int rg = bm + r; if (rg > M - 1) rg = M - 1;
        baseA[q] = rg * HID + slog * 8;
        baseB[q] = r * HID + slog * 8;  // 128 stacked hi/lo rows, ld=256
    }

    for (int t = 0; t < 4; ++t) {
        if (t > 0) __syncthreads();
        const int k0 = t << 6;
#pragma unroll
        for (int q = 0; q < 4; q++)
            gload_lds16(h + baseA[q] + k0, &Al[(wv * 4 + q) * 512]);
#pragma unroll
        for (int q = 0; q < 4; q++)
            gload_lds16(linWt + baseB[q] + k0, &Bl[(wv * 4 + q) * 512]);
        asm volatile("s_waitcnt vmcnt(0)" ::: "memory");
        __syncthreads();
#pragma unroll
        for (int kk = 0; kk < 2; kk++) {
            bf16x8 af[2], bfr[8];
#pragma unroll
            for (int m = 0; m < 2; m++) {
                int r = wr + 16 * m + lr;
                int ph = (kk * 4 + lg) ^ (r & 7);
                af[m] = *(const bf16x8*)&Al[r * 64 + ph * 8];
            }
#pragma unroll
            for (int n = 0; n < 8; n++) {
                int c = n * 16 + lr;
                int ph = (kk * 4 + lg) ^ (c & 7);
                bfr[n] = *(const bf16x8*)&Bl[c * 64 + ph * 8];
            }
#pragma unroll
            for (int m = 0; m < 2; m++)
#pragma unroll
                for (int n = 0; n < 8; n++)
                    acc[m][n] = __builtin_amdgcn_mfma_f32_16x16x32_bf16(
                        af[m], bfr[n], acc[m][n], 0, 0, 0);
        }
    }

    float b4[4];
#pragma unroll
    for (int n = 0; n < 4; n++) b4[n] = bias[n * 16 + lr];
#pragma unroll
    for (int m = 0; m < 2; m++) {
#pragma unroll
        for (int reg = 0; reg < 4; reg++) {
            const int row = bm + wr + 16 * m + lg * 4 + reg;
            float v0 = acc[m][0][reg] + acc[m][4][reg] + b4[0];
            float v1 = acc[m][1][reg] + acc[m][5][reg] + b4[1];
            float v2 = acc[m][2][reg] + acc[m][6][reg] + b4[2];
            float v3 = acc[m][3][reg] + acc[m][7][reg] + b4[3];
            float mx = fmaxf(fmaxf(v0, v1), fmaxf(v2, v3));
#pragma unroll
            for (int s = 1; s < 16; s <<= 1) mx = fmaxf(mx, __shfl_xor(mx, s));
            float sum = expf(v0 - mx) + expf(v1 - mx) + expf(v2 - mx) + expf(v3 - mx);
#pragma unroll
            for (int s = 1; s < 16; s <<= 1) sum += __shfl_xor(sum, s);
            const float lse = mx + logf(sum);
            if (row < M) {
                float* orow = out + (size_t)row * OUT_CH + lr;
                orow[0]  = v0 - lse;
                orow[16] = v1 - lse;
                orow[32] = v2 - lse;
                orow[48] = v3 - lse;
            }
        }
    }
}

// ---------------------------------------------------------------------------
extern "C" void kernel_launch(void* const* d_in, const int* in_sizes, int n_in,
                              void* d_out, int out_size, void* d_ws, size_t ws_size,
                              hipStream_t stream) {
    const float* x     = (const float*)d_in[0];
    const int*   eidx  = (const int*)d_in[1];
    const int*   etype = (const int*)d_in[2];
    const float* W1    = (const float*)d_in[3];
    const float* root1 = (const float*)d_in[4];
    const float* b1    = (const float*)d_in[5];
    const float* W2    = (const float*)d_in[6];
    const float* root2 = (const float*)d_in[7];
    const float* b2    = (const float*)d_in[8];
    const float* linW  = (const float*)d_in[9];
    const float* linb  = (const float*)d_in[10];
    float* out = (float*)d_out;
    const int* srcI = eidx;
    const int* dstI = eidx + E_EDGES;

    char* ws = (char*)d_ws;
    size_t off = 0;
    auto alloc = [&](size_t bytes) {
        size_t o = off;
        off += (bytes + 255) & ~(size_t)255;
        return ws + o;
    };
    // --- persistent through layer 2 (allocated FIRST) ---
    unsigned short* hb1   = (unsigned short*)alloc((size_t)N_NODES * HID * 2);
    unsigned short* hb2   = (unsigned short*)alloc((size_t)N_NODES * HID * 2);
    unsigned short* Wt2   = (unsigned short*)alloc((size_t)256 * 2304 * 2);
    unsigned short* linWt = (unsigned short*)alloc((size_t)128 * 256 * 2);
    int* ekey    = (int*)alloc((size_t)E_EDGES * 4);
    int* relOffs = (int*)alloc((size_t)N_NODES * 9 * 4);
    const size_t persistEnd = off;   // ~56.6 MB
    // --- dead by layer 2 (reusable region) ---
    unsigned short* xb  = (unsigned short*)alloc((size_t)N_NODES * IN_CH * 2);
    unsigned short* Wt1 = (unsigned short*)alloc((size_t)256 * 1152 * 2);
    int* deg    = (int*)alloc((size_t)N_NODES * 4);
    int* cursor = (int*)alloc((size_t)N_NODES * 4);
    int* offs   = (int*)alloc((size_t)(N_NODES + 1) * 4);
    int* bsum   = (int*)alloc((size_t)256 * 4);
    // L1 agg: after ALL live-during-L1 buffers ([50000,1024] bf16 = 102.4 MB;
    // proven fit). Also reused for L2 chunked path.
    unsigned short* aggL1 = (unsigned short*)(ws + off);
    // L2 single-chunk agg overlaps the dead region ([50000,2048] bf16 = 204.8
    // MB needed from persistEnd). Deterministic branch on fixed ws_size.
    unsigned short* aggL2 = (unsigned short*)(ws + persistEnd);
    const bool l2single =
        (ws_size > persistEnd) &&
        (ws_size - persistEnd >= (size_t)N_NODES * NREL * HID * 2);

    k_prep<<<PREP_CVT + PREP_WT1 + PREP_WT2 + PREP_WT3, 256, 0, stream>>>(
        x, xb, root1, W1, Wt1, root2, W2, Wt2, linW, linWt);
    hipMemsetAsync(deg, 0, (size_t)N_NODES * 4, stream);
    hipMemsetAsync(cursor, 0, (size_t)N_NODES * 4, stream);
    k_deg<<<(E_EDGES + 255) / 256, 256, 0, stream>>>(dstI, deg);
    const int nb = (N_NODES + 255) / 256;  // 196
    k_scanA<<<nb, 256, 0, stream>>>(deg, offs, bsum);
    k_scanB<<<1, 256, 0, stream>>>(bsum, nb);
    k_scanC<<<nb, 256, 0, stream>>>(offs, bsum);
    k_place<<<(E_EDGES + 255) / 256, 256, 0, stream>>>(srcI, dstI, etype, offs, cursor, ekey);
    k_wsort<<<(N_NODES + 3) / 4, 256, 0, stream>>>(offs, ekey, relOffs);

    auto mkGrid = [](int M, int& rpx) {
        int nRow = (M + 127) / 128;
        rpx = (nRow + 7) / 8;
        return 16 * rpx;
    };

    // ---- Layer 1: agg (one pass, all 50k) + one fused GEMM, K = 1152 ----
    {
        int rpx;
        const int nG = mkGrid(N_NODES, rpx);
        k_agg8<IN_CH><<<(N_NODES + 3) / 4, 256, 0, stream>>>(xb, relOffs, ekey, aggL1,
                                                             0, N_NODES);
        k_mgemm<<<nG, 256, 0, stream>>>(xb, IN_CH, IN_CH, aggL1, NREL * IN_CH,
                                        Wt1, 1152, 1152, b1, hb1, N_NODES, rpx);
    }

    // ---- Layer 2: K = 2304; single chunk if workspace allows, else two ----
    if (l2single) {
        int rpx;
        const int nG = mkGrid(N_NODES, rpx);
        k_agg8<HID><<<(N_NODES + 3) / 4, 256, 0, stream>>>(hb1, relOffs, ekey, aggL2,
                                                           0, N_NODES);
        k_mgemm<<<nG, 256, 0, stream>>>(hb1, HID, HID, aggL2, NREL * HID,
                                        Wt2, 2304, 2304, b2, hb2, N_NODES, rpx);
    } else {
        for (int c = 0; c < 2; c++) {
            const int base = c * HALF1;
            int rpx;
            const int nG = mkGrid(HALF1, rpx);
            k_agg8<HID><<<(HALF1 + 3) / 4, 256, 0, stream>>>(hb1, relOffs, ekey, aggL1,
                                                             base, HALF1);
            k_mgemm<<<nG, 256, 0, stream>>>(hb1 + (size_t)base * HID, HID, HID,
                                            aggL1, NREL * HID, Wt2, 2304, 2304, b2,
                                            hb2 + (size_t)base * HID, HALF1, rpx);
        }
    }

    // ---- Final linear (MFMA, split-W) + log_softmax ----
    k_final3<<<(N_NODES + 127) / 128, 256, 0, stream>>>(hb2, linWt, linb, out, N_NODES);
}